// Round 6
// baseline (2591.726 us; speedup 1.0000x reference)
//
#include <hip/hip_runtime.h>
#include <hip/hip_bf16.h>

typedef _Float16 half8  __attribute__((ext_vector_type(8)));
typedef _Float16 half4_t __attribute__((ext_vector_type(4)));
typedef float    floatx4 __attribute__((ext_vector_type(4)));
typedef int      intx4   __attribute__((ext_vector_type(4)));

#define B_DIM   16384
#define IN_D    2048
#define HV_D    8192
#define NC      1000
#define NCP     1024
#define SCORES_N (B_DIM * NC)

// async global->LDS, 16B per lane; LDS side is wave-uniform base + lane*16
#define GLD16(gp, lp) __builtin_amdgcn_global_load_lds( \
    (const __attribute__((address_space(1))) void*)(gp), \
    (__attribute__((address_space(3))) void*)(lp), 16, 0, 0)

// ---------- P1: x (fp32) -> x_h (fp16 round-nearest). Single-precision path: ----------
// products x_h * (+-1) are exact in fp16, MFMA accumulates fp32; only error is the
// x->fp16 truncation (sigma ~3e-4 relative), hv error sigma ~0.012 vs hv sigma ~45.
__global__ void k_split(const float* __restrict__ x, _Float16* __restrict__ xh) {
    size_t i = (size_t)blockIdx.x * 256 + threadIdx.x;
    floatx4 v = ((const floatx4*)x)[i];
    half4_t h;
#pragma unroll
    for (int j = 0; j < 4; ++j) h[j] = (_Float16)v[j];
    ((half4_t*)xh)[i] = h;
}

// ---------- P2: proj [K=2048][N=8192] fp32 -> projT [N][K] fp16 (LDS-tiled) ----------
__global__ void k_transpose_proj(const float* __restrict__ p, _Float16* __restrict__ pT) {
    __shared__ float tile[64][65];
    const int t = threadIdx.x;
    const int nt = blockIdx.x * 64;
    const int kt = blockIdx.y * 64;
    const int tr = t >> 4, tc = (t & 15) * 4;
#pragma unroll
    for (int s = 0; s < 4; ++s) {
        int r = tr + s * 16;
        floatx4 v = *(const floatx4*)&p[(size_t)(kt + r) * HV_D + nt + tc];
        tile[r][tc] = v[0]; tile[r][tc + 1] = v[1];
        tile[r][tc + 2] = v[2]; tile[r][tc + 3] = v[3];
    }
    __syncthreads();
#pragma unroll
    for (int s = 0; s < 4; ++s) {
        int rn = tr + s * 16;
        half4_t o;
#pragma unroll
        for (int j = 0; j < 4; ++j) o[j] = (_Float16)tile[tc + j][rn];
        *(half4_t*)&pT[(size_t)(nt + rn) * IN_D + kt + tc] = o;
    }
}

// ---------- P3: class_hv [8192][1000] fp32 -> classT [1024][8192] i8 ----------
__global__ void k_pack_class(const float* __restrict__ c, signed char* __restrict__ cT) {
    __shared__ signed char tile[64][68];
    const int t = threadIdx.x;
    const int nt = blockIdx.x * 64;
    const int kt = blockIdx.y * 64;
    const int nl = t & 63;
    const int n = nt + nl;
#pragma unroll
    for (int s = 0; s < 16; ++s) {
        const int kl = s * 4 + (t >> 6);
        signed char v = 0;
        if (n < NC) {
            float f = c[(size_t)(kt + kl) * NC + n];
            v = (f >= 0.f) ? (signed char)1 : (signed char)-1;
        }
        tile[kl][nl] = v;
    }
    __syncthreads();
    const int wn = t >> 2;
    const int wk = (t & 3) * 16;
    intx4 o;
    signed char* ob = (signed char*)&o;
#pragma unroll
    for (int j = 0; j < 16; ++j) ob[j] = tile[wk + j][wn];
    *(intx4*)&cT[(size_t)(nt + wn) * HV_D + kt + wk] = o;
}

// ---------- G1: hv = x@proj, SINGLE fp16 pass, binarize, write fp32 + i8 ----------
// R5-proven loop structure, minus the Dekker-lo pass: half the MFMA work, half the
// A staging. LDS 16+32 = 48 KB -> 3 blocks/CU (__launch_bounds__(256,3)) = 12 waves/CU
// for more cross-block overlap of the __syncthreads vmcnt drain. 128(M)x256(N), BK=64,
// 4 waves 2x2, wave tile 64x128, proven-zero-conflict swizzle family.
__launch_bounds__(256, 3)
__global__ void k_gemm1(const _Float16* __restrict__ xh,
                        const _Float16* __restrict__ pT,
                        float* __restrict__ hv_out, signed char* __restrict__ hvb) {
    __shared__ _Float16 sAh[128 * 64];   // 16 KB
    __shared__ _Float16 sB [256 * 64];   // 32 KB
    const int t = threadIdx.x;
    const int w = t >> 6, l = t & 63;
    const int m0 = blockIdx.y * 128, n0 = blockIdx.x * 256;
    const int wm = (w >> 1) * 64, wn = (w & 1) * 128;
    const int lm = l & 15, kq = l >> 4;
    const int srow  = w * 8 + (l >> 3);                  // + i*32
    const int scol  = (((l & 7) ^ ((l >> 3) & 7))) * 8;  // swizzled source chunk (f16 units)
    const int sbyte = w * 1024 + l * 16;                 // + i*4096

    floatx4 acc[4][8] = {};

    for (int k0 = 0; k0 < IN_D; k0 += 64) {
        __syncthreads();
#pragma unroll
        for (int i = 0; i < 4; ++i) {
            const size_t ga = (size_t)(m0 + srow + i * 32) * IN_D + k0 + scol;
            GLD16(xh + ga, (char*)sAh + sbyte + i * 4096);
        }
#pragma unroll
        for (int i = 0; i < 8; ++i) {
            const size_t gb = (size_t)(n0 + srow + i * 32) * IN_D + k0 + scol;
            GLD16(pT + gb, (char*)sB + sbyte + i * 4096);
        }
        __syncthreads();
#pragma unroll
        for (int ks = 0; ks < 2; ++ks) {
            const int csw = ((ks * 4 + kq) ^ (lm & 7)) * 8;   // swizzled slot (f16 units)
            half8 b[8];
#pragma unroll
            for (int ns = 0; ns < 8; ++ns)
                b[ns] = *(const half8*)&sB[(wn + ns * 16 + lm) * 64 + csw];
#pragma unroll
            for (int ms = 0; ms < 4; ++ms) {
                half8 a = *(const half8*)&sAh[(wm + ms * 16 + lm) * 64 + csw];
#pragma unroll
                for (int ns = 0; ns < 8; ++ns)
                    acc[ms][ns] = __builtin_amdgcn_mfma_f32_16x16x32_f16(a, b[ns], acc[ms][ns], 0, 0, 0);
            }
        }
    }

    // epilogue: C/D layout col=lane&15, row=(lane>>4)*4+reg (plain stores)
#pragma unroll
    for (int ms = 0; ms < 4; ++ms) {
#pragma unroll
        for (int ns = 0; ns < 8; ++ns) {
            const int m = m0 + wm + ms * 16 + kq * 4;
            const int n = n0 + wn + ns * 16 + lm;
#pragma unroll
            for (int r = 0; r < 4; ++r) {
                const int pos = (acc[ms][ns][r] >= 0.f);
                const size_t o = (size_t)(m + r) * HV_D + n;
                hv_out[o] = pos ? 1.f : -1.f;
                hvb[o] = (signed char)(pos ? 1 : -1);
            }
        }
    }
}

// ---------- G2: scores = hv_bin @ class_hv, exact in i8 (K=8192) ----------
// R5 config verbatim (part of the 1661us baseline): 64x256 block, BK=128, dbuf
// 80KB -> 2 blocks/CU, counted vmcnt(10) (never 0 in loop), peeled last tile.
__launch_bounds__(256, 2)
__global__ void k_gemm2(const signed char* __restrict__ hvb, const signed char* __restrict__ cT,
                        float* __restrict__ scores) {
    __shared__ signed char sA[2][64 * 128];    // 2 x  8 KB
    __shared__ signed char sB[2][256 * 128];   // 2 x 32 KB  => 80 KB total
    const int t = threadIdx.x;
    const int w = t >> 6, l = t & 63;

    const int orig = blockIdx.y * 4 + blockIdx.x;
    const int lid  = (orig & 7) * 128 + (orig >> 3);   // cpx = 1024/8 = 128
    const int bx = lid & 3, by = lid >> 2;

    const int m0 = by * 64, n0 = bx * 256;
    const int wm = (w >> 1) * 32, wn = (w & 1) * 128;  // wave tile 32x128
    const int lm = l & 15, kq = l >> 4;
    const int srow  = w * 8 + (l >> 3);                   // + i*32
    const int scol  = (((l & 7) ^ ((l >> 3) & 7))) * 16;  // swizzled source chunk (bytes)
    const int sbyte = w * 1024 + l * 16;                  // + i*4096

    intx4 acc[2][8] = {};

#define G2_STAGE(buf, kt) do { \
    const int k0_ = (kt) * 128; \
    _Pragma("unroll") \
    for (int i = 0; i < 2; ++i) \
        GLD16(hvb + (size_t)(m0 + srow + i * 32) * HV_D + k0_ + scol, \
              (char*)&sA[buf][0] + sbyte + i * 4096); \
    _Pragma("unroll") \
    for (int i = 0; i < 8; ++i) \
        GLD16(cT + (size_t)(n0 + srow + i * 32) * HV_D + k0_ + scol, \
              (char*)&sB[buf][0] + sbyte + i * 4096); \
} while (0)

#define G2_COMPUTE(buf) do { \
    _Pragma("unroll") \
    for (int ks = 0; ks < 2; ++ks) { \
        const int csw = ((ks * 4 + kq) ^ (lm & 7)) * 16; \
        intx4 b[8]; \
        _Pragma("unroll") \
        for (int ns = 0; ns < 8; ++ns) \
            b[ns] = *(const intx4*)&sB[buf][(wn + ns * 16 + lm) * 128 + csw]; \
        _Pragma("unroll") \
        for (int ms = 0; ms < 2; ++ms) { \
            intx4 a = *(const intx4*)&sA[buf][(wm + ms * 16 + lm) * 128 + csw]; \
            _Pragma("unroll") \
            for (int ns = 0; ns < 8; ++ns) \
                acc[ms][ns] = __builtin_amdgcn_mfma_i32_16x16x64_i8(a, b[ns], acc[ms][ns], 0, 0, 0); \
        } \
    } \
} while (0)

    // prologue: k-tile 0 into buf0
    G2_STAGE(0, 0);

#pragma unroll 1
    for (int kt = 0; kt < 63; ++kt) {
        const int cur = kt & 1;
        __builtin_amdgcn_s_barrier();              // WAR: all waves done with buf[cur^1]
        if (cur == 0) G2_STAGE(1, kt + 1); else G2_STAGE(0, kt + 1);
        asm volatile("s_waitcnt vmcnt(10)" ::: "memory");   // force buf[cur]'s 10 loads
        __builtin_amdgcn_sched_barrier(0);
        __builtin_amdgcn_s_barrier();              // RAW: cur's data visible to all
        __builtin_amdgcn_sched_barrier(0);
        if (cur == 0) G2_COMPUTE(0); else G2_COMPUTE(1);
    }
    // peeled last tile: kt=63, cur=1
    __builtin_amdgcn_s_barrier();
    asm volatile("s_waitcnt vmcnt(0)" ::: "memory");
    __builtin_amdgcn_sched_barrier(0);
    __builtin_amdgcn_s_barrier();
    __builtin_amdgcn_sched_barrier(0);
    G2_COMPUTE(1);

#undef G2_STAGE
#undef G2_COMPUTE

#pragma unroll
    for (int ms = 0; ms < 2; ++ms) {
#pragma unroll
        for (int ns = 0; ns < 8; ++ns) {
            const int m = m0 + wm + ms * 16 + kq * 4;
            const int n = n0 + wn + ns * 16 + lm;
            if (n < NC) {
#pragma unroll
                for (int r = 0; r < 4; ++r)
                    __builtin_nontemporal_store((float)acc[ms][ns][r],
                                                &scores[(size_t)(m + r) * NC + n]);
            }
        }
    }
}

extern "C" void kernel_launch(void* const* d_in, const int* in_sizes, int n_in,
                              void* d_out, int out_size, void* d_ws, size_t ws_size,
                              hipStream_t stream) {
    const float* x    = (const float*)d_in[0];   // [16384][2048]
    const float* proj = (const float*)d_in[1];   // [2048][8192]
    const float* chv  = (const float*)d_in[2];   // [8192][1000]
    float* out    = (float*)d_out;
    float* scores = out;                          // [16384][1000]
    float* hv_out = out + (size_t)SCORES_N;       // [16384][8192]

    // workspace layout (xl slot now unused; offsets kept stable)
    char* ws = (char*)d_ws;
    _Float16*    xh  = (_Float16*)(ws);                         //  64 MiB
    _Float16*    pT  = (_Float16*)(ws + (size_t)134217728);     //  32 MiB
    signed char* cT  = (signed char*)(ws + (size_t)167772160);  //   8 MiB
    signed char* hvb = (signed char*)(ws + (size_t)176160768);  // 128 MiB

    k_split<<<(B_DIM * IN_D / 4) / 256, 256, 0, stream>>>(x, xh);
    k_transpose_proj<<<dim3(HV_D / 64, IN_D / 64), 256, 0, stream>>>(proj, pT);
    k_pack_class<<<dim3(NCP / 64, HV_D / 64), 256, 0, stream>>>(chv, cT);
    // single gemm1 dispatch (~450-500us expected): visible above the ~387us fills
    k_gemm1<<<dim3(HV_D / 256, B_DIM / 128), 256, 0, stream>>>(xh, pT, hv_out, hvb);
    k_gemm2<<<dim3(NCP / 256, B_DIM / 64), 256, 0, stream>>>(hvb, cT, scores);
}

// Round 7
// 1409.719 us; speedup vs baseline: 1.8385x; 1.8385x over previous
//
#include <hip/hip_runtime.h>
#include <hip/hip_bf16.h>

typedef _Float16 half8  __attribute__((ext_vector_type(8)));
typedef _Float16 half4_t __attribute__((ext_vector_type(4)));
typedef float    floatx4 __attribute__((ext_vector_type(4)));
typedef int      intx4   __attribute__((ext_vector_type(4)));

#define B_DIM   16384
#define IN_D    2048
#define HV_D    8192
#define NC      1000
#define NCP     1024
#define SCORES_N (B_DIM * NC)

// async global->LDS, 16B per lane; LDS side is wave-uniform base + lane*16
#define GLD16(gp, lp) __builtin_amdgcn_global_load_lds( \
    (const __attribute__((address_space(1))) void*)(gp), \
    (__attribute__((address_space(3))) void*)(lp), 16, 0, 0)

// ---------- P1: x (fp32) -> x_h (fp16 round-nearest). Single-precision path ----------
// (validated R6: absmax=10 passes). Products x_h*(+-1) exact in fp16, fp32 MFMA accum.
__global__ void k_split(const float* __restrict__ x, _Float16* __restrict__ xh) {
    size_t i = (size_t)blockIdx.x * 256 + threadIdx.x;
    floatx4 v = ((const floatx4*)x)[i];
    half4_t h;
#pragma unroll
    for (int j = 0; j < 4; ++j) h[j] = (_Float16)v[j];
    ((half4_t*)xh)[i] = h;
}

// ---------- P2: proj [K=2048][N=8192] fp32 -> projT [N][K] fp16 (LDS-tiled) ----------
__global__ void k_transpose_proj(const float* __restrict__ p, _Float16* __restrict__ pT) {
    __shared__ float tile[64][65];
    const int t = threadIdx.x;
    const int nt = blockIdx.x * 64;
    const int kt = blockIdx.y * 64;
    const int tr = t >> 4, tc = (t & 15) * 4;
#pragma unroll
    for (int s = 0; s < 4; ++s) {
        int r = tr + s * 16;
        floatx4 v = *(const floatx4*)&p[(size_t)(kt + r) * HV_D + nt + tc];
        tile[r][tc] = v[0]; tile[r][tc + 1] = v[1];
        tile[r][tc + 2] = v[2]; tile[r][tc + 3] = v[3];
    }
    __syncthreads();
#pragma unroll
    for (int s = 0; s < 4; ++s) {
        int rn = tr + s * 16;
        half4_t o;
#pragma unroll
        for (int j = 0; j < 4; ++j) o[j] = (_Float16)tile[tc + j][rn];
        *(half4_t*)&pT[(size_t)(nt + rn) * IN_D + kt + tc] = o;
    }
}

// ---------- P3: class_hv [8192][1000] fp32 -> classT [1024][8192] i8 ----------
__global__ void k_pack_class(const float* __restrict__ c, signed char* __restrict__ cT) {
    __shared__ signed char tile[64][68];
    const int t = threadIdx.x;
    const int nt = blockIdx.x * 64;
    const int kt = blockIdx.y * 64;
    const int nl = t & 63;
    const int n = nt + nl;
#pragma unroll
    for (int s = 0; s < 16; ++s) {
        const int kl = s * 4 + (t >> 6);
        signed char v = 0;
        if (n < NC) {
            float f = c[(size_t)(kt + kl) * NC + n];
            v = (f >= 0.f) ? (signed char)1 : (signed char)-1;
        }
        tile[kl][nl] = v;
    }
    __syncthreads();
    const int wn = t >> 2;
    const int wk = (t & 3) * 16;
    intx4 o;
    signed char* ob = (signed char*)&o;
#pragma unroll
    for (int j = 0; j < 16; ++j) ob[j] = tile[wk + j][wn];
    *(intx4*)&cT[(size_t)(nt + wn) * HV_D + kt + wk] = o;
}

// ---------- G1: hv = x@proj, SINGLE fp16 pass, binarize, write fp32 + i8 ----------
// R5-proven configuration EXACTLY (2 blocks/CU, two half-M 2048-block dispatches,
// LDS_Block_Size 65536, plain stores -> measured mandatory WRITE_SIZE), with only the
// Dekker-lo pass removed (validated R6: absmax=10 passes). sAh declared [2][...] and
// only [0] used: pads LDS to exactly 64 KB so HW caps residency at 2 blocks/CU --
// R6's 3-blocks/CU + 4096-block grid caused 8x HBM write amplification (L2 partial-
// line thrash: WRITE_SIZE 5.1GB vs 0.64GB mandatory). Do NOT raise occupancy here.
__launch_bounds__(256, 2)
__global__ void k_gemm1(const _Float16* __restrict__ xh,
                        const _Float16* __restrict__ pT,
                        float* __restrict__ hv_out, signed char* __restrict__ hvb,
                        int mbase) {
    __shared__ _Float16 sAh[2][128 * 64];   // 32 KB ([1] is residency-cap padding)
    __shared__ _Float16 sB [256 * 64];      // 32 KB
    const int t = threadIdx.x;
    const int w = t >> 6, l = t & 63;
    const int m0 = mbase + blockIdx.y * 128, n0 = blockIdx.x * 256;
    const int wm = (w >> 1) * 64, wn = (w & 1) * 128;
    const int lm = l & 15, kq = l >> 4;
    const int srow  = w * 8 + (l >> 3);                  // + i*32
    const int scol  = (((l & 7) ^ ((l >> 3) & 7))) * 8;  // swizzled source chunk (f16 units)
    const int sbyte = w * 1024 + l * 16;                 // + i*4096

    floatx4 acc[4][8] = {};

    for (int k0 = 0; k0 < IN_D; k0 += 64) {
        __syncthreads();
#pragma unroll
        for (int i = 0; i < 4; ++i) {
            const size_t ga = (size_t)(m0 + srow + i * 32) * IN_D + k0 + scol;
            GLD16(xh + ga, (char*)&sAh[0][0] + sbyte + i * 4096);
        }
#pragma unroll
        for (int i = 0; i < 8; ++i) {
            const size_t gb = (size_t)(n0 + srow + i * 32) * IN_D + k0 + scol;
            GLD16(pT + gb, (char*)sB + sbyte + i * 4096);
        }
        __syncthreads();
#pragma unroll
        for (int ks = 0; ks < 2; ++ks) {
            const int csw = ((ks * 4 + kq) ^ (lm & 7)) * 8;   // swizzled slot (f16 units)
            half8 b[8];
#pragma unroll
            for (int ns = 0; ns < 8; ++ns)
                b[ns] = *(const half8*)&sB[(wn + ns * 16 + lm) * 64 + csw];
#pragma unroll
            for (int ms = 0; ms < 4; ++ms) {
                half8 a = *(const half8*)&sAh[0][(wm + ms * 16 + lm) * 64 + csw];
#pragma unroll
                for (int ns = 0; ns < 8; ++ns)
                    acc[ms][ns] = __builtin_amdgcn_mfma_f32_16x16x32_f16(a, b[ns], acc[ms][ns], 0, 0, 0);
            }
        }
    }

    // epilogue: C/D layout col=lane&15, row=(lane>>4)*4+reg (plain stores, R5-exact)
#pragma unroll
    for (int ms = 0; ms < 4; ++ms) {
#pragma unroll
        for (int ns = 0; ns < 8; ++ns) {
            const int m = m0 + wm + ms * 16 + kq * 4;
            const int n = n0 + wn + ns * 16 + lm;
#pragma unroll
            for (int r = 0; r < 4; ++r) {
                const int pos = (acc[ms][ns][r] >= 0.f);
                const size_t o = (size_t)(m + r) * HV_D + n;
                hv_out[o] = pos ? 1.f : -1.f;
                hvb[o] = (signed char)(pos ? 1 : -1);
            }
        }
    }
}

// ---------- G2: scores = hv_bin @ class_hv, exact in i8 (K=8192) ----------
// R5 config verbatim: 64x256 block, BK=128, dbuf 80KB -> 2 blocks/CU, counted
// vmcnt(10) (never 0 in loop), peeled last tile.
__launch_bounds__(256, 2)
__global__ void k_gemm2(const signed char* __restrict__ hvb, const signed char* __restrict__ cT,
                        float* __restrict__ scores) {
    __shared__ signed char sA[2][64 * 128];    // 2 x  8 KB
    __shared__ signed char sB[2][256 * 128];   // 2 x 32 KB  => 80 KB total
    const int t = threadIdx.x;
    const int w = t >> 6, l = t & 63;

    const int orig = blockIdx.y * 4 + blockIdx.x;
    const int lid  = (orig & 7) * 128 + (orig >> 3);   // cpx = 1024/8 = 128
    const int bx = lid & 3, by = lid >> 2;

    const int m0 = by * 64, n0 = bx * 256;
    const int wm = (w >> 1) * 32, wn = (w & 1) * 128;  // wave tile 32x128
    const int lm = l & 15, kq = l >> 4;
    const int srow  = w * 8 + (l >> 3);                   // + i*32
    const int scol  = (((l & 7) ^ ((l >> 3) & 7))) * 16;  // swizzled source chunk (bytes)
    const int sbyte = w * 1024 + l * 16;                  // + i*4096

    intx4 acc[2][8] = {};

#define G2_STAGE(buf, kt) do { \
    const int k0_ = (kt) * 128; \
    _Pragma("unroll") \
    for (int i = 0; i < 2; ++i) \
        GLD16(hvb + (size_t)(m0 + srow + i * 32) * HV_D + k0_ + scol, \
              (char*)&sA[buf][0] + sbyte + i * 4096); \
    _Pragma("unroll") \
    for (int i = 0; i < 8; ++i) \
        GLD16(cT + (size_t)(n0 + srow + i * 32) * HV_D + k0_ + scol, \
              (char*)&sB[buf][0] + sbyte + i * 4096); \
} while (0)

#define G2_COMPUTE(buf) do { \
    _Pragma("unroll") \
    for (int ks = 0; ks < 2; ++ks) { \
        const int csw = ((ks * 4 + kq) ^ (lm & 7)) * 16; \
        intx4 b[8]; \
        _Pragma("unroll") \
        for (int ns = 0; ns < 8; ++ns) \
            b[ns] = *(const intx4*)&sB[buf][(wn + ns * 16 + lm) * 128 + csw]; \
        _Pragma("unroll") \
        for (int ms = 0; ms < 2; ++ms) { \
            intx4 a = *(const intx4*)&sA[buf][(wm + ms * 16 + lm) * 128 + csw]; \
            _Pragma("unroll") \
            for (int ns = 0; ns < 8; ++ns) \
                acc[ms][ns] = __builtin_amdgcn_mfma_i32_16x16x64_i8(a, b[ns], acc[ms][ns], 0, 0, 0); \
        } \
    } \
} while (0)

    // prologue: k-tile 0 into buf0
    G2_STAGE(0, 0);

#pragma unroll 1
    for (int kt = 0; kt < 63; ++kt) {
        const int cur = kt & 1;
        __builtin_amdgcn_s_barrier();              // WAR: all waves done with buf[cur^1]
        if (cur == 0) G2_STAGE(1, kt + 1); else G2_STAGE(0, kt + 1);
        asm volatile("s_waitcnt vmcnt(10)" ::: "memory");   // force buf[cur]'s 10 loads
        __builtin_amdgcn_sched_barrier(0);
        __builtin_amdgcn_s_barrier();              // RAW: cur's data visible to all
        __builtin_amdgcn_sched_barrier(0);
        if (cur == 0) G2_COMPUTE(0); else G2_COMPUTE(1);
    }
    // peeled last tile: kt=63, cur=1
    __builtin_amdgcn_s_barrier();
    asm volatile("s_waitcnt vmcnt(0)" ::: "memory");
    __builtin_amdgcn_sched_barrier(0);
    __builtin_amdgcn_s_barrier();
    __builtin_amdgcn_sched_barrier(0);
    G2_COMPUTE(1);

#undef G2_STAGE
#undef G2_COMPUTE

#pragma unroll
    for (int ms = 0; ms < 2; ++ms) {
#pragma unroll
        for (int ns = 0; ns < 8; ++ns) {
            const int m = m0 + wm + ms * 16 + kq * 4;
            const int n = n0 + wn + ns * 16 + lm;
            if (n < NC) {
#pragma unroll
                for (int r = 0; r < 4; ++r)
                    __builtin_nontemporal_store((float)acc[ms][ns][r],
                                                &scores[(size_t)(m + r) * NC + n]);
            }
        }
    }
}

extern "C" void kernel_launch(void* const* d_in, const int* in_sizes, int n_in,
                              void* d_out, int out_size, void* d_ws, size_t ws_size,
                              hipStream_t stream) {
    const float* x    = (const float*)d_in[0];   // [16384][2048]
    const float* proj = (const float*)d_in[1];   // [2048][8192]
    const float* chv  = (const float*)d_in[2];   // [8192][1000]
    float* out    = (float*)d_out;
    float* scores = out;                          // [16384][1000]
    float* hv_out = out + (size_t)SCORES_N;       // [16384][8192]

    // workspace layout (xl slot unused; offsets kept stable)
    char* ws = (char*)d_ws;
    _Float16*    xh  = (_Float16*)(ws);                         //  64 MiB
    _Float16*    pT  = (_Float16*)(ws + (size_t)134217728);     //  32 MiB
    signed char* cT  = (signed char*)(ws + (size_t)167772160);  //   8 MiB
    signed char* hvb = (signed char*)(ws + (size_t)176160768);  // 128 MiB

    k_split<<<(B_DIM * IN_D / 4) / 256, 256, 0, stream>>>(x, xh);
    k_transpose_proj<<<dim3(HV_D / 64, IN_D / 64), 256, 0, stream>>>(proj, pT);
    k_pack_class<<<dim3(NCP / 64, HV_D / 64), 256, 0, stream>>>(chv, cT);
    // gemm1 as two half-M dispatches (R5-proven grid/occupancy; mandatory-write config)
    k_gemm1<<<dim3(HV_D / 256, B_DIM / 256), 256, 0, stream>>>(xh, pT, hv_out, hvb, 0);
    k_gemm1<<<dim3(HV_D / 256, B_DIM / 256), 256, 0, stream>>>(xh, pT, hv_out, hvb, B_DIM / 2);
    k_gemm2<<<dim3(NCP / 256, B_DIM / 64), 256, 0, stream>>>(hvb, cT, scores);
}